// Round 2
// baseline (300.161 us; speedup 1.0000x reference)
//
#include <hip/hip_runtime.h>
#include <stdint.h>

namespace {
constexpr int B_ = 32;
constexpr int T_ = 2048;
constexpr int K_ = 512;
constexpr int MM = 1024;   // MAX_MASKED
constexpr int MU = 1024;   // MAX_UNMASKED
constexpr float EPS = 1e-5f;
constexpr int ROWS_PER_REGION = B_ * MU;  // 32768 rows per output region
}  // namespace

// FP32 in / FP32 out (absmax 7.8e-3 = ref bf16 floor).
// R6 restructure: regions 0 (tok gather) and 2 (pe gather) share the same
// index/validity -> merged into ONE wave that writes both rows (one index
// load, tok+pe reads co-issued). Merged-gather waves and LN waves are
// interleaved 1:1 across the grid so HBM reads and writes overlap for the
// whole kernel instead of running as serialized one-sided phases.
// NOTE R5 (kept): __builtin_nontemporal_* REGRESSED (~44 -> ~76 us).
__global__ __launch_bounds__(256) void mae_mask_kernel(
    const float* __restrict__ tok,      // (B,T,K)
    const float* __restrict__ pe,       // (T,K)
    const float* __restrict__ mw,       // (K,1)
    const float* __restrict__ gamma,    // (K,)
    const float* __restrict__ beta,     // (K,)
    const int* __restrict__ mask_idx,   // (B,MM)
    const int* __restrict__ unmask_idx, // (B,MU)
    const int* __restrict__ n_m,        // (B,)
    const int* __restrict__ n_u,        // (B,)
    float* __restrict__ out)            // 3*B*1024*K fp32
{
    const int lane = threadIdx.x & 63;
    const int wave = threadIdx.x >> 6;
    const int wg   = (blockIdx.x << 2) | wave;   // global wave id, [0, 65536)
    const int sel  = wg & 1;                     // 0 = merged gather, 1 = LN
    const int r    = wg >> 1;                    // row index within region, [0, 32768)
    const int b    = r >> 10;
    const int j    = r & (MU - 1);
    const int c    = lane << 3;                  // 8 fp32 per lane

    if (sel == 0) {
        // ---- regions 0 & 2: unmasked_embeddings + unmasked_positions ----
        float4* o0 = (float4*)(out + (size_t)r * K_ + c);                       // region 0
        float4* o2 = (float4*)(out + (size_t)(2 * ROWS_PER_REGION + r) * K_ + c); // region 2
        float4 t0 = make_float4(0.f, 0.f, 0.f, 0.f), t1 = t0;
        float4 p0 = t0, p1 = t0;
        if (j < n_u[b]) {
            const int idx = unmask_idx[(b << 10) + j];
            const float4* ts = (const float4*)(tok + ((size_t)b * T_ + (size_t)idx) * K_ + c);
            const float4* ps = (const float4*)(pe + (size_t)idx * K_ + c);
            t0 = ts[0]; t1 = ts[1];
            p0 = ps[0]; p1 = ps[1];
        }
        o0[0] = t0; o0[1] = t1;
        o2[0] = p0; o2[1] = p1;
    } else {
        // ---- region 1: mask_embedding = LN(mask_weight + pe[mask_idx]) ----
        float4* o1 = (float4*)(out + (size_t)(ROWS_PER_REGION + r) * K_ + c);
        float4 y0 = make_float4(0.f, 0.f, 0.f, 0.f), y1 = y0;
        if (j < n_m[b]) {
            const int idx = mask_idx[(b << 10) + j];
            const float4* pv = (const float4*)(pe + (size_t)idx * K_ + c);
            const float4* mv = (const float4*)(mw + c);
            const float4 p0 = pv[0], p1 = pv[1];
            const float4 m0 = mv[0], m1 = mv[1];
            float x[8] = { p0.x + m0.x, p0.y + m0.y, p0.z + m0.z, p0.w + m0.w,
                           p1.x + m1.x, p1.y + m1.y, p1.z + m1.z, p1.w + m1.w };
            float s = 0.f, ss = 0.f;
            #pragma unroll
            for (int e = 0; e < 8; ++e) { s += x[e]; ss += x[e] * x[e]; }
            // 64-lane butterfly reduction (wave = 64 on gfx950)
            #pragma unroll
            for (int off = 1; off < 64; off <<= 1) {
                s  += __shfl_xor(s,  off, 64);
                ss += __shfl_xor(ss, off, 64);
            }
            const float mean = s * (1.0f / K_);
            float var = ss * (1.0f / K_) - mean * mean;
            var = var < 0.f ? 0.f : var;
            const float inv = rsqrtf(var + EPS);
            const float4* gv = (const float4*)(gamma + c);
            const float4* bv = (const float4*)(beta + c);
            const float4 g0 = gv[0], g1 = gv[1];
            const float4 b0 = bv[0], b1 = bv[1];
            const float g[8]  = { g0.x, g0.y, g0.z, g0.w, g1.x, g1.y, g1.z, g1.w };
            const float be[8] = { b0.x, b0.y, b0.z, b0.w, b1.x, b1.y, b1.z, b1.w };
            float y[8];
            #pragma unroll
            for (int e = 0; e < 8; ++e) y[e] = (x[e] - mean) * inv * g[e] + be[e];
            y0 = make_float4(y[0], y[1], y[2], y[3]);
            y1 = make_float4(y[4], y[5], y[6], y[7]);
        }
        o1[0] = y0; o1[1] = y1;
    }
}

extern "C" void kernel_launch(void* const* d_in, const int* in_sizes, int n_in,
                              void* d_out, int out_size, void* d_ws, size_t ws_size,
                              hipStream_t stream) {
    const float* tok   = (const float*)d_in[0];
    const float* pe    = (const float*)d_in[1];
    const float* mw    = (const float*)d_in[2];
    const float* gamma = (const float*)d_in[3];
    const float* beta  = (const float*)d_in[4];
    const int* mask_idx   = (const int*)d_in[5];
    const int* unmask_idx = (const int*)d_in[6];
    const int* n_m        = (const int*)d_in[7];
    const int* n_u        = (const int*)d_in[8];
    float* out = (float*)d_out;

    // 65536 waves (32768 merged-gather + 32768 LN), 4 waves/block.
    const int blocks = (2 * ROWS_PER_REGION) / 4;   // 16384
    hipLaunchKernelGGL(mae_mask_kernel, dim3(blocks), dim3(256), 0, stream,
                       tok, pe, mw, gamma, beta, mask_idx, unmask_idx,
                       n_m, n_u, out);
}

// Round 3
// 290.129 us; speedup vs baseline: 1.0346x; 1.0346x over previous
//
#include <hip/hip_runtime.h>
#include <stdint.h>

namespace {
constexpr int B_ = 32;
constexpr int T_ = 2048;
constexpr int K_ = 512;
constexpr int MM = 1024;   // MAX_MASKED
constexpr int MU = 1024;   // MAX_UNMASKED
constexpr float EPS = 1e-5f;
constexpr int ROWS0 = B_ * MU;   // unmasked_embeddings rows
constexpr int ROWS1 = B_ * MM;   // mask_embedding rows
constexpr int WAVES_PER_BLOCK = 4;
}  // namespace

// FP32 in / FP32 out (R3: pass, absmax 7.8e-3 = ref bf16 floor).
// One wave (64 lanes) per output row of K=512: 8 fp32 = 32 B/lane in & out.
// Per-wave branches are uniform (each wave handles exactly one region).
// NOTE R5: __builtin_nontemporal_* on these streams REGRESSED the kernel
// ~44 -> ~76 us (nt store defeats L2 write-combining; nt load defeats
// intra-row line reuse).
// NOTE R6 (round 2): merging regions 0+2 into one wave (dual-row writes,
// 1:1 interleave with LN waves) REGRESSED ~44 -> ~54 us: two store streams
// 64 MB apart per wave defeat write coalescing. One-row-per-wave,
// per-region-contiguous is the optimum found.
__global__ __launch_bounds__(256) void mae_mask_kernel(
    const float* __restrict__ tok,      // (B,T,K)
    const float* __restrict__ pe,       // (T,K)
    const float* __restrict__ mw,       // (K,1)
    const float* __restrict__ gamma,    // (K,)
    const float* __restrict__ beta,     // (K,)
    const int* __restrict__ mask_idx,   // (B,MM)
    const int* __restrict__ unmask_idx, // (B,MU)
    const int* __restrict__ n_m,        // (B,)
    const int* __restrict__ n_u,        // (B,)
    float* __restrict__ out)            // 3*B*1024*K fp32
{
    const int lane = threadIdx.x & 63;
    const int wave = threadIdx.x >> 6;
    const int row  = blockIdx.x * WAVES_PER_BLOCK + wave;
    const int c    = lane << 3;  // starting element, 8 fp32 per lane

    float4* orow = (float4*)(out + (size_t)row * K_ + c);

    if (row < ROWS0) {
        // ---- unmasked_embeddings: gather token rows ----
        const int b = row >> 10, j = row & (MU - 1);
        float4 v0 = make_float4(0.f, 0.f, 0.f, 0.f), v1 = v0;
        if (j < n_u[b]) {
            const int idx = unmask_idx[(b << 10) + j];
            const float4* src = (const float4*)(tok + ((size_t)b * T_ + (size_t)idx) * K_ + c);
            v0 = src[0]; v1 = src[1];
        }
        orow[0] = v0; orow[1] = v1;
    } else if (row < ROWS0 + ROWS1) {
        // ---- mask_embedding: LN(mask_weight + pe[mask_idx]) ----
        const int r = row - ROWS0;
        const int b = r >> 10, i = r & (MM - 1);
        float4 o0 = make_float4(0.f, 0.f, 0.f, 0.f), o1 = o0;
        if (i < n_m[b]) {
            const int idx = mask_idx[(b << 10) + i];
            const float4* pv = (const float4*)(pe + (size_t)idx * K_ + c);
            const float4* mv = (const float4*)(mw + c);
            const float4 p0 = pv[0], p1 = pv[1];
            const float4 m0 = mv[0], m1 = mv[1];
            float x[8] = { p0.x + m0.x, p0.y + m0.y, p0.z + m0.z, p0.w + m0.w,
                           p1.x + m1.x, p1.y + m1.y, p1.z + m1.z, p1.w + m1.w };
            float s = 0.f, ss = 0.f;
            #pragma unroll
            for (int e = 0; e < 8; ++e) { s += x[e]; ss += x[e] * x[e]; }
            // 64-lane butterfly reduction (wave = 64 on gfx950)
            #pragma unroll
            for (int off = 1; off < 64; off <<= 1) {
                s  += __shfl_xor(s,  off, 64);
                ss += __shfl_xor(ss, off, 64);
            }
            const float mean = s * (1.0f / K_);
            float var = ss * (1.0f / K_) - mean * mean;
            var = var < 0.f ? 0.f : var;
            const float inv = rsqrtf(var + EPS);
            const float4* gv = (const float4*)(gamma + c);
            const float4* bv = (const float4*)(beta + c);
            const float4 g0 = gv[0], g1 = gv[1];
            const float4 b0 = bv[0], b1 = bv[1];
            const float g[8]  = { g0.x, g0.y, g0.z, g0.w, g1.x, g1.y, g1.z, g1.w };
            const float be[8] = { b0.x, b0.y, b0.z, b0.w, b1.x, b1.y, b1.z, b1.w };
            float y[8];
            #pragma unroll
            for (int e = 0; e < 8; ++e) y[e] = (x[e] - mean) * inv * g[e] + be[e];
            o0 = make_float4(y[0], y[1], y[2], y[3]);
            o1 = make_float4(y[4], y[5], y[6], y[7]);
        }
        orow[0] = o0; orow[1] = o1;
    } else {
        // ---- unmasked_positions: gather pe rows ----
        const int r = row - (ROWS0 + ROWS1);
        const int b = r >> 10, j = r & (MU - 1);
        float4 v0 = make_float4(0.f, 0.f, 0.f, 0.f), v1 = v0;
        if (j < n_u[b]) {
            const int idx = unmask_idx[(b << 10) + j];
            const float4* src = (const float4*)(pe + (size_t)idx * K_ + c);
            v0 = src[0]; v1 = src[1];
        }
        orow[0] = v0; orow[1] = v1;
    }
}

extern "C" void kernel_launch(void* const* d_in, const int* in_sizes, int n_in,
                              void* d_out, int out_size, void* d_ws, size_t ws_size,
                              hipStream_t stream) {
    const float* tok   = (const float*)d_in[0];
    const float* pe    = (const float*)d_in[1];
    const float* mw    = (const float*)d_in[2];
    const float* gamma = (const float*)d_in[3];
    const float* beta  = (const float*)d_in[4];
    const int* mask_idx   = (const int*)d_in[5];
    const int* unmask_idx = (const int*)d_in[6];
    const int* n_m        = (const int*)d_in[7];
    const int* n_u        = (const int*)d_in[8];
    float* out = (float*)d_out;

    const int total_rows = 3 * B_ * 1024;               // 98304
    const int blocks = total_rows / WAVES_PER_BLOCK;    // 24576
    hipLaunchKernelGGL(mae_mask_kernel, dim3(blocks), dim3(256), 0, stream,
                       tok, pe, mw, gamma, beta, mask_idx, unmask_idx,
                       n_m, n_u, out);
}